// Round 1
// baseline (869.901 us; speedup 1.0000x reference)
//
#include <hip/hip_runtime.h>
#include <math.h>

#define N_NODES 100000
#define N_EDGES 1600000
#define C_IN    128
#define H_DIM   64
#define G_GRAPHS 512

// monotonic float<->uint encoding so that memset(0) == -inf for atomicMax
__device__ __forceinline__ unsigned int enc_f32(float f) {
    unsigned int u = __float_as_uint(f);
    return (u & 0x80000000u) ? ~u : (u | 0x80000000u);
}
__device__ __forceinline__ float dec_f32(unsigned int e) {
    unsigned int u = (e & 0x80000000u) ? (e & 0x7FFFFFFFu) : ~e;
    return __uint_as_float(u);
}

// K1: u1 = x @ W1 (N x 64), raw = x . pool_w, atomicMax per-graph raw max.
// wave-per-node, W1 staged in LDS.
__global__ void k1_lin1(const float* __restrict__ x, const float* __restrict__ W1,
                        const float* __restrict__ pool_w, const int* __restrict__ batch,
                        float* __restrict__ A, float* __restrict__ sc,
                        unsigned int* __restrict__ m_enc) {
    __shared__ float W1s[C_IN * H_DIM];
    for (int i = threadIdx.x; i < C_IN * H_DIM; i += blockDim.x) W1s[i] = W1[i];
    __syncthreads();
    const int lane = threadIdx.x & 63;
    const int wid  = blockIdx.x * (blockDim.x >> 6) + (threadIdx.x >> 6);
    const int nw   = gridDim.x * (blockDim.x >> 6);
    for (int n0 = wid; n0 < N_NODES; n0 += nw) {
        const int n = __builtin_amdgcn_readfirstlane(n0);
        const float* xr = x + (size_t)n * C_IN;
        // raw = x . pool_w (lane-parallel, then butterfly reduce)
        float2 xv = ((const float2*)xr)[lane];
        float pr = xv.x * pool_w[2 * lane] + xv.y * pool_w[2 * lane + 1];
        #pragma unroll
        for (int m = 32; m > 0; m >>= 1) pr += __shfl_xor(pr, m, 64);
        // u1 row: lane j = output channel j
        float acc = 0.f;
        #pragma unroll 16
        for (int k = 0; k < C_IN; ++k) acc = fmaf(xr[k], W1s[k * H_DIM + lane], acc);
        A[(size_t)n * H_DIM + lane] = acc;
        if (lane == 0) {
            sc[n] = pr;
            atomicMax(&m_enc[batch[n]], enc_f32(pr));
        }
    }
}

// K2: e = exp(raw - m[g]); z[g] += e
__global__ void k2_exp(const int* __restrict__ batch, const unsigned int* __restrict__ m_enc,
                       float* __restrict__ sc, float* __restrict__ z) {
    int i = blockIdx.x * blockDim.x + threadIdx.x;
    if (i >= N_NODES) return;
    int g = batch[i];
    float e = expf(sc[i] - dec_f32(m_enc[g]));
    sc[i] = e;
    atomicAdd(&z[g], e);
}

// K3: score = e / z[g]; smax[g] = max(score)
__global__ void k3_score(const int* __restrict__ batch, const float* __restrict__ z,
                         float* __restrict__ sc, unsigned int* __restrict__ smax_enc) {
    int i = blockIdx.x * blockDim.x + threadIdx.x;
    if (i >= N_NODES) return;
    int g = batch[i];
    float s = sc[i] / z[g];
    sc[i] = s;
    atomicMax(&smax_enc[g], enc_f32(s));
}

// Ks1: agg1[dst] += u1[src]  — wave per edge, lane per channel
__global__ void ks1_scatter(const int* __restrict__ ei, const float* __restrict__ A,
                            float* __restrict__ B) {
    int t = blockIdx.x * blockDim.x + threadIdx.x;
    int e = t >> 6;
    int j = t & 63;
    if (e >= N_EDGES) return;
    int s = ei[e];
    int d = ei[N_EDGES + e];
    atomicAdd(&B[(size_t)d * H_DIM + j], A[(size_t)s * H_DIM + j]);
}

// K5: per node: mask; if kept: t1=relu(u1+agg1+b1); o1=relu(t1@W2+b2);
//     v = (o1*score)@W3 -> overwrite A row; pooling stats.
__global__ void k5_mid(const int* __restrict__ batch, const float* __restrict__ sc,
                       const unsigned int* __restrict__ smax_enc,
                       const float* __restrict__ attn,
                       const float* __restrict__ b1, const float* __restrict__ W2,
                       const float* __restrict__ b2, const float* __restrict__ W3,
                       float* __restrict__ A, const float* __restrict__ Bagg,
                       float* __restrict__ mk, float* __restrict__ cnt,
                       float* __restrict__ klsum, float* __restrict__ nkept) {
    __shared__ float W2s[H_DIM * H_DIM];
    __shared__ float W3s[H_DIM * H_DIM];
    for (int i = threadIdx.x; i < H_DIM * H_DIM; i += blockDim.x) {
        W2s[i] = W2[i];
        W3s[i] = W3[i];
    }
    __syncthreads();
    const int lane = threadIdx.x & 63;
    const int wid  = blockIdx.x * (blockDim.x >> 6) + (threadIdx.x >> 6);
    const int nw   = gridDim.x * (blockDim.x >> 6);
    const float b1l = b1[lane], b2l = b2[lane];
    for (int n = wid; n < N_NODES; n += nw) {
        int g = batch[n];
        float score = sc[n];
        float smax = dec_f32(smax_enc[g]);
        float thresh = fminf(smax - 1e-7f, 0.05f);
        bool kept = score > thresh;
        if (lane == 0) mk[n] = kept ? 1.f : 0.f;
        if (!kept) continue;
        float t1 = fmaxf(A[(size_t)n * H_DIM + lane] + Bagg[(size_t)n * H_DIM + lane] + b1l, 0.f);
        float o1 = b2l;
        #pragma unroll 8
        for (int k = 0; k < H_DIM; ++k) o1 = fmaf(__shfl(t1, k, 64), W2s[k * H_DIM + lane], o1);
        o1 = fmaxf(o1, 0.f);
        float v = 0.f;
        #pragma unroll 8
        for (int k = 0; k < H_DIM; ++k) v = fmaf(__shfl(o1, k, 64), W3s[k * H_DIM + lane], v);
        v *= score;  // out = o1*score; v = out@W3 = score*(o1@W3)
        A[(size_t)n * H_DIM + lane] = v;
        if (lane == 0) {
            atomicAdd(&cnt[g], 1.f);
            float a = attn[n];
            float kl = a * (logf(a) - logf(score + 1e-14f));
            atomicAdd(&klsum[g], kl);
            atomicAdd(nkept, 1.f);
        }
    }
}

// Ks2: agg2[dst] += v[src] for edges with both endpoints kept (rare)
__global__ void ks2_scatter(const int* __restrict__ ei, const float* __restrict__ mk,
                            const float* __restrict__ A, float* __restrict__ B) {
    int e = blockIdx.x * blockDim.x + threadIdx.x;
    if (e >= N_EDGES) return;
    int s = ei[e], d = ei[N_EDGES + e];
    if (mk[s] == 0.f || mk[d] == 0.f) return;
    const float* vr = A + (size_t)s * H_DIM;
    float* br = B + (size_t)d * H_DIM;
    #pragma unroll 16
    for (int j = 0; j < H_DIM; ++j) atomicAdd(&br[j], vr[j]);
}

// K6: kept nodes: t = relu(v + agg2 + b3); o2 = relu(t@W4 + b4); gout[g] += o2
__global__ void k6_out(const int* __restrict__ batch, const float* __restrict__ mk,
                       const float* __restrict__ b3, const float* __restrict__ W4,
                       const float* __restrict__ b4,
                       const float* __restrict__ A, const float* __restrict__ B,
                       float* __restrict__ gout) {
    __shared__ float W4s[H_DIM * H_DIM];
    for (int i = threadIdx.x; i < H_DIM * H_DIM; i += blockDim.x) W4s[i] = W4[i];
    __syncthreads();
    const int lane = threadIdx.x & 63;
    const int wid  = blockIdx.x * (blockDim.x >> 6) + (threadIdx.x >> 6);
    const int nw   = gridDim.x * (blockDim.x >> 6);
    const float b3l = b3[lane], b4l = b4[lane];
    for (int n = wid; n < N_NODES; n += nw) {
        if (mk[n] == 0.f) continue;
        float t = fmaxf(A[(size_t)n * H_DIM + lane] + B[(size_t)n * H_DIM + lane] + b3l, 0.f);
        float o2 = b4l;
        #pragma unroll 8
        for (int k = 0; k < H_DIM; ++k) o2 = fmaf(__shfl(t, k, 64), W4s[k * H_DIM + lane], o2);
        o2 = fmaxf(o2, 0.f);
        atomicAdd(&gout[(size_t)batch[n] * H_DIM + lane], o2);
    }
}

// K7: pred[g] = gout[g].Wl + bl; attn_loss[g] = klsum/max(cnt,1); ratio
__global__ void k7_final(const float* __restrict__ gout, const float* __restrict__ Wl,
                         const float* __restrict__ bl, const float* __restrict__ klsum,
                         const float* __restrict__ cnt, const float* __restrict__ nkept,
                         float* __restrict__ out) {
    int g = blockIdx.x;
    int lane = threadIdx.x;
    float p = gout[(size_t)g * H_DIM + lane] * Wl[lane];
    #pragma unroll
    for (int m = 32; m > 0; m >>= 1) p += __shfl_xor(p, m, 64);
    if (lane == 0) {
        out[g] = p + bl[0];
        out[G_GRAPHS + g] = klsum[g] / fmaxf(cnt[g], 1.f);
        if (g == 0) out[2 * G_GRAPHS] = nkept[0] * (1.f / (float)N_NODES);
    }
}

extern "C" void kernel_launch(void* const* d_in, const int* in_sizes, int n_in,
                              void* d_out, int out_size, void* d_ws, size_t ws_size,
                              hipStream_t stream) {
    const float* x      = (const float*)d_in[0];
    const int*   ei     = (const int*)d_in[1];
    const int*   batch  = (const int*)d_in[2];
    const float* attn   = (const float*)d_in[3];
    const float* W1     = (const float*)d_in[4];
    const float* b1     = (const float*)d_in[5];
    const float* W2     = (const float*)d_in[6];
    const float* b2     = (const float*)d_in[7];
    const float* pool_w = (const float*)d_in[8];
    const float* W3     = (const float*)d_in[9];
    const float* b3     = (const float*)d_in[10];
    const float* W4     = (const float*)d_in[11];
    const float* b4     = (const float*)d_in[12];
    const float* Wl     = (const float*)d_in[13];
    const float* bl     = (const float*)d_in[14];
    float* out = (float*)d_out;

    // workspace layout
    float* A  = (float*)d_ws;                       // N*64: u1 then v
    float* B  = A + (size_t)N_NODES * H_DIM;        // N*64: agg1 then agg2
    float* sc = B + (size_t)N_NODES * H_DIM;        // N: raw -> e -> score
    float* mk = sc + N_NODES;                       // N: mask as float
    unsigned int* m_enc    = (unsigned int*)(mk + N_NODES);  // G
    float*        z        = (float*)(m_enc + G_GRAPHS);     // G
    unsigned int* smax_enc = (unsigned int*)(z + G_GRAPHS);  // G
    float*        cnt      = (float*)(smax_enc + G_GRAPHS);  // G
    float*        klsum    = cnt + G_GRAPHS;                 // G
    float*        gout     = klsum + G_GRAPHS;               // G*64
    float*        nkept    = gout + (size_t)G_GRAPHS * H_DIM; // 1
    size_t small_bytes = (size_t)((char*)(nkept + 1) - (char*)m_enc);

    hipMemsetAsync(B, 0, (size_t)N_NODES * H_DIM * sizeof(float), stream);
    hipMemsetAsync(m_enc, 0, small_bytes, stream);

    k1_lin1<<<1024, 256, 0, stream>>>(x, W1, pool_w, batch, A, sc, m_enc);
    k2_exp<<<(N_NODES + 255) / 256, 256, 0, stream>>>(batch, m_enc, sc, z);
    k3_score<<<(N_NODES + 255) / 256, 256, 0, stream>>>(batch, z, sc, smax_enc);
    ks1_scatter<<<(N_EDGES * 64) / 256, 256, 0, stream>>>(ei, A, B);
    k5_mid<<<512, 256, 0, stream>>>(batch, sc, smax_enc, attn, b1, W2, b2, W3,
                                    A, B, mk, cnt, klsum, nkept);
    hipMemsetAsync(B, 0, (size_t)N_NODES * H_DIM * sizeof(float), stream);
    ks2_scatter<<<(N_EDGES + 255) / 256, 256, 0, stream>>>(ei, mk, A, B);
    k6_out<<<512, 256, 0, stream>>>(batch, mk, b3, W4, b4, A, B, gout);
    k7_final<<<G_GRAPHS, 64, 0, stream>>>(gout, Wl, bl, klsum, cnt, nkept, out);
}

// Round 2
// 823.715 us; speedup vs baseline: 1.0561x; 1.0561x over previous
//
#include <hip/hip_runtime.h>
#include <math.h>

#define N_NODES 100000
#define N_EDGES 1600000
#define C_IN    128
#define H_DIM   64
#define G_GRAPHS 512

// monotonic float<->uint encoding so that memset(0) == -inf for atomicMax
__device__ __forceinline__ unsigned int enc_f32(float f) {
    unsigned int u = __float_as_uint(f);
    return (u & 0x80000000u) ? ~u : (u | 0x80000000u);
}
__device__ __forceinline__ float dec_f32(unsigned int e) {
    unsigned int u = (e & 0x80000000u) ? (e & 0x7FFFFFFFu) : ~e;
    return __uint_as_float(u);
}

// ---------------- CSR build (counting sort by dst) ----------------

__global__ void khist(const int* __restrict__ ei, int* __restrict__ deg) {
    int e = blockIdx.x * blockDim.x + threadIdx.x;
    if (e < N_EDGES) atomicAdd(&deg[ei[N_EDGES + e]], 1);
}

// per-chunk (1024 elems) exclusive scan; chunk totals to blk[]
__global__ void kscan1(const int* __restrict__ deg, int* __restrict__ off,
                       int* __restrict__ blk) {
    __shared__ int ts[256];
    int t = threadIdx.x;
    int base = blockIdx.x * 1024 + 4 * t;
    int d0 = 0, d1 = 0, d2 = 0, d3 = 0;
    if (base + 3 < N_NODES) {
        int4 v = *(const int4*)(deg + base);
        d0 = v.x; d1 = v.y; d2 = v.z; d3 = v.w;
    } else {
        if (base     < N_NODES) d0 = deg[base];
        if (base + 1 < N_NODES) d1 = deg[base + 1];
        if (base + 2 < N_NODES) d2 = deg[base + 2];
        if (base + 3 < N_NODES) d3 = deg[base + 3];
    }
    int s = d0 + d1 + d2 + d3;
    ts[t] = s;
    __syncthreads();
    for (int ofs = 1; ofs < 256; ofs <<= 1) {
        int v = (t >= ofs) ? ts[t - ofs] : 0;
        __syncthreads();
        ts[t] += v;
        __syncthreads();
    }
    int excl = ts[t] - s;
    if (base     < N_NODES) off[base]     = excl;
    if (base + 1 < N_NODES) off[base + 1] = excl + d0;
    if (base + 2 < N_NODES) off[base + 2] = excl + d0 + d1;
    if (base + 3 < N_NODES) off[base + 3] = excl + d0 + d1 + d2;
    if (t == 255) blk[blockIdx.x] = ts[255];
}

#define N_CHUNKS 98  // ceil(100000/1024)

__global__ void kscan2(int* __restrict__ blk) {
    __shared__ int ts[128];
    int t = threadIdx.x;
    int v = (t < N_CHUNKS) ? blk[t] : 0;
    ts[t] = v;
    __syncthreads();
    for (int ofs = 1; ofs < 128; ofs <<= 1) {
        int u = (t >= ofs) ? ts[t - ofs] : 0;
        __syncthreads();
        ts[t] += u;
        __syncthreads();
    }
    if (t < N_CHUNKS) blk[t] = ts[t] - v;  // exclusive chunk offsets
}

__global__ void kscan3(int* __restrict__ off, int* __restrict__ cursor,
                       const int* __restrict__ blk) {
    int i = blockIdx.x * blockDim.x + threadIdx.x;
    if (i >= N_NODES) return;
    int v = off[i] + blk[i >> 10];
    off[i] = v;
    cursor[i] = v;
}

__global__ void kbucket(const int* __restrict__ ei, int* __restrict__ cursor,
                        int* __restrict__ srcs) {
    int e = blockIdx.x * blockDim.x + threadIdx.x;
    if (e >= N_EDGES) return;
    int s = ei[e];
    int d = ei[N_EDGES + e];
    int pos = atomicAdd(&cursor[d], 1);  // cursor ends at row end
    srcs[pos] = s;
}

// ---------------- Node pipeline ----------------

// K1: A = x @ W1 (N x 64), raw = x . pool_w, per-graph raw max.
__global__ void k1_lin1(const float* __restrict__ x, const float* __restrict__ W1,
                        const float* __restrict__ pool_w, const int* __restrict__ batch,
                        float* __restrict__ A, float* __restrict__ sc,
                        unsigned int* __restrict__ m_enc) {
    __shared__ float W1s[C_IN * H_DIM];
    for (int i = threadIdx.x; i < C_IN * H_DIM; i += blockDim.x) W1s[i] = W1[i];
    __syncthreads();
    const int lane = threadIdx.x & 63;
    const int wid  = blockIdx.x * (blockDim.x >> 6) + (threadIdx.x >> 6);
    const int nw   = gridDim.x * (blockDim.x >> 6);
    for (int n0 = wid; n0 < N_NODES; n0 += nw) {
        const int n = __builtin_amdgcn_readfirstlane(n0);
        const float* xr = x + (size_t)n * C_IN;
        float2 xv = ((const float2*)xr)[lane];
        float pr = xv.x * pool_w[2 * lane] + xv.y * pool_w[2 * lane + 1];
        #pragma unroll
        for (int m = 32; m > 0; m >>= 1) pr += __shfl_xor(pr, m, 64);
        float acc = 0.f;
        #pragma unroll 16
        for (int k = 0; k < C_IN; ++k) acc = fmaf(xr[k], W1s[k * H_DIM + lane], acc);
        A[(size_t)n * H_DIM + lane] = acc;
        if (lane == 0) {
            sc[n] = pr;
            atomicMax(&m_enc[batch[n]], enc_f32(pr));
        }
    }
}

__global__ void k2_exp(const int* __restrict__ batch, const unsigned int* __restrict__ m_enc,
                       float* __restrict__ sc, float* __restrict__ z) {
    int i = blockIdx.x * blockDim.x + threadIdx.x;
    if (i >= N_NODES) return;
    int g = batch[i];
    float e = expf(sc[i] - dec_f32(m_enc[g]));
    sc[i] = e;
    atomicAdd(&z[g], e);
}

__global__ void k3_score(const int* __restrict__ batch, const float* __restrict__ z,
                         float* __restrict__ sc, unsigned int* __restrict__ smax_enc) {
    int i = blockIdx.x * blockDim.x + threadIdx.x;
    if (i >= N_NODES) return;
    int g = batch[i];
    float s = sc[i] / z[g];
    sc[i] = s;
    atomicMax(&smax_enc[g], enc_f32(s));
}

// Kagg: B[d] = sum_{src in in(d)} A[src]   (no atomics, writes B fully)
__global__ void kagg(const int* __restrict__ off, const int* __restrict__ endp,
                     const int* __restrict__ srcs, const float* __restrict__ A,
                     float* __restrict__ B) {
    const int lane = threadIdx.x & 63;
    const int wid  = blockIdx.x * (blockDim.x >> 6) + (threadIdx.x >> 6);
    const int nw   = gridDim.x * (blockDim.x >> 6);
    for (int n = wid; n < N_NODES; n += nw) {
        int s0 = off[n];
        int e0 = endp[n];
        float sum = 0.f;
        int i = s0;
        while (i < e0) {
            int cnt = e0 - i;
            if (cnt > 64) cnt = 64;
            int sv = srcs[i + (lane < cnt ? lane : 0)];
            #pragma unroll 4
            for (int j = 0; j < cnt; ++j) {
                int s = __shfl(sv, j, 64);
                sum += A[(size_t)s * H_DIM + lane];
            }
            i += cnt;
        }
        B[(size_t)n * H_DIM + lane] = sum;
    }
}

// K4: mask + kept-list compaction + KL stats (thread per node)
__global__ void k4_mask(const int* __restrict__ batch, const float* __restrict__ sc,
                        const unsigned int* __restrict__ smax_enc,
                        const float* __restrict__ attn,
                        float* __restrict__ mk, int* __restrict__ klist,
                        int* __restrict__ kcount, float* __restrict__ cnt,
                        float* __restrict__ klsum) {
    int i = blockIdx.x * blockDim.x + threadIdx.x;
    if (i >= N_NODES) return;
    int g = batch[i];
    float s = sc[i];
    float thresh = fminf(dec_f32(smax_enc[g]) - 1e-7f, 0.05f);
    bool kept = s > thresh;
    mk[i] = kept ? 1.f : 0.f;
    if (kept) {
        int pos = atomicAdd(kcount, 1);
        klist[pos] = i;
        atomicAdd(&cnt[g], 1.f);
        float a = attn[i];
        atomicAdd(&klsum[g], a * (logf(a) - logf(s + 1e-14f)));
    }
}

// K5: kept nodes only: t1=relu(u1+agg1+b1); o1=relu(t1@W2+b2); A[n]=score*(o1@W3)
__global__ void k5_kept(const int* __restrict__ klist, const int* __restrict__ kcount,
                        const float* __restrict__ sc,
                        const float* __restrict__ b1, const float* __restrict__ W2,
                        const float* __restrict__ b2, const float* __restrict__ W3,
                        float* __restrict__ A, const float* __restrict__ B) {
    __shared__ float W2s[H_DIM * H_DIM];
    __shared__ float W3s[H_DIM * H_DIM];
    for (int i = threadIdx.x; i < H_DIM * H_DIM; i += blockDim.x) {
        W2s[i] = W2[i];
        W3s[i] = W3[i];
    }
    __syncthreads();
    const int lane = threadIdx.x & 63;
    const int wid  = blockIdx.x * (blockDim.x >> 6) + (threadIdx.x >> 6);
    const int nw   = gridDim.x * (blockDim.x >> 6);
    const int kc = *kcount;
    const float b1l = b1[lane], b2l = b2[lane];
    for (int idx = wid; idx < kc; idx += nw) {
        int n = klist[idx];
        float t1 = fmaxf(A[(size_t)n * H_DIM + lane] + B[(size_t)n * H_DIM + lane] + b1l, 0.f);
        float o1 = b2l;
        #pragma unroll 8
        for (int k = 0; k < H_DIM; ++k) o1 = fmaf(__shfl(t1, k, 64), W2s[k * H_DIM + lane], o1);
        o1 = fmaxf(o1, 0.f);
        float v = 0.f;
        #pragma unroll 8
        for (int k = 0; k < H_DIM; ++k) v = fmaf(__shfl(o1, k, 64), W3s[k * H_DIM + lane], v);
        A[(size_t)n * H_DIM + lane] = v * sc[n];
    }
}

// K6: kept nodes only: agg2 over kept in-neighbors via CSR; t=relu(v+agg2+b3);
//     o2=relu(t@W4+b4); gout[g] += o2
__global__ void k6_fused(const int* __restrict__ klist, const int* __restrict__ kcount,
                         const int* __restrict__ batch, const float* __restrict__ mk,
                         const int* __restrict__ off, const int* __restrict__ endp,
                         const int* __restrict__ srcs,
                         const float* __restrict__ b3, const float* __restrict__ W4,
                         const float* __restrict__ b4,
                         const float* __restrict__ A, float* __restrict__ gout) {
    __shared__ float W4s[H_DIM * H_DIM];
    for (int i = threadIdx.x; i < H_DIM * H_DIM; i += blockDim.x) W4s[i] = W4[i];
    __syncthreads();
    const int lane = threadIdx.x & 63;
    const int wid  = blockIdx.x * (blockDim.x >> 6) + (threadIdx.x >> 6);
    const int nw   = gridDim.x * (blockDim.x >> 6);
    const int kc = *kcount;
    const float b3l = b3[lane], b4l = b4[lane];
    for (int idx = wid; idx < kc; idx += nw) {
        int n = klist[idx];
        float agg = 0.f;
        int s0 = off[n], e0 = endp[n];
        for (int i = s0; i < e0; ++i) {
            int s = srcs[i];
            if (mk[s] != 0.f) agg += A[(size_t)s * H_DIM + lane];
        }
        float t = fmaxf(A[(size_t)n * H_DIM + lane] + agg + b3l, 0.f);
        float o2 = b4l;
        #pragma unroll 8
        for (int k = 0; k < H_DIM; ++k) o2 = fmaf(__shfl(t, k, 64), W4s[k * H_DIM + lane], o2);
        o2 = fmaxf(o2, 0.f);
        atomicAdd(&gout[(size_t)batch[n] * H_DIM + lane], o2);
    }
}

__global__ void k7_final(const float* __restrict__ gout, const float* __restrict__ Wl,
                         const float* __restrict__ bl, const float* __restrict__ klsum,
                         const float* __restrict__ cnt, const int* __restrict__ kcount,
                         float* __restrict__ out) {
    int g = blockIdx.x;
    int lane = threadIdx.x;
    float p = gout[(size_t)g * H_DIM + lane] * Wl[lane];
    #pragma unroll
    for (int m = 32; m > 0; m >>= 1) p += __shfl_xor(p, m, 64);
    if (lane == 0) {
        out[g] = p + bl[0];
        out[G_GRAPHS + g] = klsum[g] / fmaxf(cnt[g], 1.f);
        if (g == 0) out[2 * G_GRAPHS] = (float)(*kcount) * (1.f / (float)N_NODES);
    }
}

extern "C" void kernel_launch(void* const* d_in, const int* in_sizes, int n_in,
                              void* d_out, int out_size, void* d_ws, size_t ws_size,
                              hipStream_t stream) {
    const float* x      = (const float*)d_in[0];
    const int*   ei     = (const int*)d_in[1];
    const int*   batch  = (const int*)d_in[2];
    const float* attn   = (const float*)d_in[3];
    const float* W1     = (const float*)d_in[4];
    const float* b1     = (const float*)d_in[5];
    const float* W2     = (const float*)d_in[6];
    const float* b2     = (const float*)d_in[7];
    const float* pool_w = (const float*)d_in[8];
    const float* W3     = (const float*)d_in[9];
    const float* b3     = (const float*)d_in[10];
    const float* W4     = (const float*)d_in[11];
    const float* b4     = (const float*)d_in[12];
    const float* Wl     = (const float*)d_in[13];
    const float* bl     = (const float*)d_in[14];
    float* out = (float*)d_out;

    // workspace layout (floats/ints are both 4B)
    float* A      = (float*)d_ws;                           // N*64: u1 then v
    float* B      = A + (size_t)N_NODES * H_DIM;            // N*64: agg1
    float* sc     = B + (size_t)N_NODES * H_DIM;            // N
    float* mk     = sc + N_NODES;                           // N
    int*   deg    = (int*)(mk + N_NODES);                   // N (memset 0); later aliased as klist
    int*   off    = deg + N_NODES;                          // N
    int*   cursor = off + N_NODES;                          // N (becomes row-end after kbucket)
    int*   srcs   = cursor + N_NODES;                       // E
    int*   blk    = srcs + N_EDGES;                         // N_CHUNKS
    // small zeroed block:
    unsigned int* m_enc    = (unsigned int*)(blk + 128);    // G
    float*        z        = (float*)(m_enc + G_GRAPHS);    // G
    unsigned int* smax_enc = (unsigned int*)(z + G_GRAPHS); // G
    float*        cnt      = (float*)(smax_enc + G_GRAPHS); // G
    float*        klsum    = cnt + G_GRAPHS;                // G
    float*        gout     = klsum + G_GRAPHS;              // G*64
    int*          kcount   = (int*)(gout + (size_t)G_GRAPHS * H_DIM); // 1
    int*          klist    = deg;  // deg dead after kscan1; k4 runs much later
    size_t small_bytes = (size_t)((char*)(kcount + 1) - (char*)m_enc);

    hipMemsetAsync(deg, 0, (size_t)N_NODES * sizeof(int), stream);
    hipMemsetAsync(m_enc, 0, small_bytes, stream);

    // CSR build
    khist  <<<N_EDGES / 256, 256, 0, stream>>>(ei, deg);
    kscan1 <<<N_CHUNKS, 256, 0, stream>>>(deg, off, blk);
    kscan2 <<<1, 128, 0, stream>>>(blk);
    kscan3 <<<(N_NODES + 255) / 256, 256, 0, stream>>>(off, cursor, blk);
    kbucket<<<N_EDGES / 256, 256, 0, stream>>>(ei, cursor, srcs);

    // node pipeline
    k1_lin1<<<1024, 256, 0, stream>>>(x, W1, pool_w, batch, A, sc, m_enc);
    k2_exp <<<(N_NODES + 255) / 256, 256, 0, stream>>>(batch, m_enc, sc, z);
    k3_score<<<(N_NODES + 255) / 256, 256, 0, stream>>>(batch, z, sc, smax_enc);
    kagg   <<<2048, 256, 0, stream>>>(off, cursor, srcs, A, B);
    k4_mask<<<(N_NODES + 255) / 256, 256, 0, stream>>>(batch, sc, smax_enc, attn,
                                                       mk, klist, kcount, cnt, klsum);
    k5_kept<<<128, 256, 0, stream>>>(klist, kcount, sc, b1, W2, b2, W3, A, B);
    k6_fused<<<128, 256, 0, stream>>>(klist, kcount, batch, mk, off, cursor, srcs,
                                      b3, W4, b4, A, gout);
    k7_final<<<G_GRAPHS, 64, 0, stream>>>(gout, Wl, bl, klsum, cnt, kcount, out);
}

// Round 3
// 530.426 us; speedup vs baseline: 1.6400x; 1.5529x over previous
//
#include <hip/hip_runtime.h>
#include <math.h>

#define N_NODES 100000
#define N_EDGES 1600000
#define C_IN    128
#define H_DIM   64
#define G_GRAPHS 512

// monotonic float<->uint encoding so that memset(0) == -inf for atomicMax
__device__ __forceinline__ unsigned int enc_f32(float f) {
    unsigned int u = __float_as_uint(f);
    return (u & 0x80000000u) ? ~u : (u | 0x80000000u);
}
__device__ __forceinline__ float dec_f32(unsigned int e) {
    unsigned int u = (e & 0x80000000u) ? (e & 0x7FFFFFFFu) : ~e;
    return __uint_as_float(u);
}

// K1: raw = x . pool_w for all nodes (streams x once, BW-bound); per-graph max.
__global__ void k1_pool(const float* __restrict__ x, const float* __restrict__ pool_w,
                        const int* __restrict__ batch,
                        float* __restrict__ sc, unsigned int* __restrict__ m_enc) {
    __shared__ float pw[C_IN];
    for (int i = threadIdx.x; i < C_IN; i += blockDim.x) pw[i] = pool_w[i];
    __syncthreads();
    const int lane = threadIdx.x & 63;
    const int wid  = blockIdx.x * (blockDim.x >> 6) + (threadIdx.x >> 6);
    const int nw   = gridDim.x * (blockDim.x >> 6);
    const float pw0 = pw[2 * lane], pw1 = pw[2 * lane + 1];
    for (int n = wid; n < N_NODES; n += nw) {
        float2 xv = ((const float2*)(x + (size_t)n * C_IN))[lane];
        float pr = xv.x * pw0 + xv.y * pw1;
        #pragma unroll
        for (int m = 32; m > 0; m >>= 1) pr += __shfl_xor(pr, m, 64);
        if (lane == 0) {
            sc[n] = pr;
            atomicMax(&m_enc[batch[n]], enc_f32(pr));
        }
    }
}

__global__ void k2_exp(const int* __restrict__ batch, const unsigned int* __restrict__ m_enc,
                       float* __restrict__ sc, float* __restrict__ z) {
    int i = blockIdx.x * blockDim.x + threadIdx.x;
    if (i >= N_NODES) return;
    int g = batch[i];
    float e = expf(sc[i] - dec_f32(m_enc[g]));
    sc[i] = e;
    atomicAdd(&z[g], e);
}

__global__ void k3_score(const int* __restrict__ batch, const float* __restrict__ z,
                         float* __restrict__ sc, unsigned int* __restrict__ smax_enc) {
    int i = blockIdx.x * blockDim.x + threadIdx.x;
    if (i >= N_NODES) return;
    int g = batch[i];
    float s = sc[i] / z[g];
    sc[i] = s;
    atomicMax(&smax_enc[g], enc_f32(s));
}

// K4: mask + kept-list compaction + KL stats; zero agg rows for kept nodes.
__global__ void k4_mask(const int* __restrict__ batch, const float* __restrict__ sc,
                        const unsigned int* __restrict__ smax_enc,
                        const float* __restrict__ attn,
                        float* __restrict__ mk, int* __restrict__ klist,
                        int* __restrict__ kcount, float* __restrict__ cnt,
                        float* __restrict__ klsum, float* __restrict__ B) {
    int i = blockIdx.x * blockDim.x + threadIdx.x;
    if (i >= N_NODES) return;
    int g = batch[i];
    float s = sc[i];
    float thresh = fminf(dec_f32(smax_enc[g]) - 1e-7f, 0.05f);
    bool kept = s > thresh;
    mk[i] = kept ? 1.f : 0.f;
    if (kept) {
        int pos = atomicAdd(kcount, 1);
        klist[pos] = i;
        atomicAdd(&cnt[g], 1.f);
        float a = attn[i];
        atomicAdd(&klsum[g], a * (logf(a) - logf(s + 1e-14f)));
        float* br = B + (size_t)i * H_DIM;
        #pragma unroll
        for (int j = 0; j < H_DIM; ++j) br[j] = 0.f;
    }
}

// K5: one pass over all edges. For edges with kept dst: compute u1[src] column
// on the fly and atomicAdd into B[dst]. Edges with BOTH endpoints kept go to elist.
__global__ void k5_edges(const int* __restrict__ ei, const float* __restrict__ mk,
                         const float* __restrict__ x, const float* __restrict__ W1,
                         float* __restrict__ B, int* __restrict__ elist,
                         int* __restrict__ ecount) {
    __shared__ float W1s[C_IN * H_DIM];
    for (int i = threadIdx.x; i < C_IN * H_DIM; i += blockDim.x) W1s[i] = W1[i];
    __syncthreads();
    const int lane = threadIdx.x & 63;
    const int wid  = blockIdx.x * (blockDim.x >> 6) + (threadIdx.x >> 6);
    int e = wid * 64 + lane;
    bool valid = e < N_EDGES;
    int s = valid ? ei[e] : 0;
    int d = valid ? ei[N_EDGES + e] : 0;
    bool kd = valid && (mk[d] != 0.f);
    bool ks = valid && (mk[s] != 0.f);
    if (kd && ks) {
        int p = atomicAdd(ecount, 1);
        elist[p] = e;
    }
    unsigned long long bal = __ballot(kd);
    while (bal) {
        int j = __ffsll((long long)bal) - 1;
        bal &= bal - 1;
        int ss = __builtin_amdgcn_readfirstlane(__shfl(s, j, 64));
        int dd = __builtin_amdgcn_readfirstlane(__shfl(d, j, 64));
        const float* xr = x + (size_t)ss * C_IN;
        float acc = 0.f;
        #pragma unroll 16
        for (int k = 0; k < C_IN; ++k) acc = fmaf(xr[k], W1s[k * H_DIM + lane], acc);
        atomicAdd(&B[(size_t)dd * H_DIM + lane], acc);
    }
}

// K6: kept nodes: u1self = x[n]@W1; t1 = relu(u1self + agg1 + b1);
// o1 = relu(t1@W2+b2); A[n] = score*(o1@W3). Reset B[n]=0 for layer-2 agg.
__global__ void k6_kept(const int* __restrict__ klist, const int* __restrict__ kcount,
                        const float* __restrict__ sc, const float* __restrict__ x,
                        const float* __restrict__ W1,
                        const float* __restrict__ b1, const float* __restrict__ W2,
                        const float* __restrict__ b2, const float* __restrict__ W3,
                        float* __restrict__ A, float* __restrict__ B) {
    __shared__ float W1s[C_IN * H_DIM];
    __shared__ float W2s[H_DIM * H_DIM];
    __shared__ float W3s[H_DIM * H_DIM];
    for (int i = threadIdx.x; i < C_IN * H_DIM; i += blockDim.x) W1s[i] = W1[i];
    for (int i = threadIdx.x; i < H_DIM * H_DIM; i += blockDim.x) {
        W2s[i] = W2[i];
        W3s[i] = W3[i];
    }
    __syncthreads();
    const int lane = threadIdx.x & 63;
    const int wid  = blockIdx.x * (blockDim.x >> 6) + (threadIdx.x >> 6);
    const int nw   = gridDim.x * (blockDim.x >> 6);
    const int kc = *kcount;
    const float b1l = b1[lane], b2l = b2[lane];
    for (int idx = wid; idx < kc; idx += nw) {
        int n = __builtin_amdgcn_readfirstlane(klist[idx]);
        const float* xr = x + (size_t)n * C_IN;
        float u = 0.f;
        #pragma unroll 16
        for (int k = 0; k < C_IN; ++k) u = fmaf(xr[k], W1s[k * H_DIM + lane], u);
        float t1 = fmaxf(u + B[(size_t)n * H_DIM + lane] + b1l, 0.f);
        B[(size_t)n * H_DIM + lane] = 0.f;  // reset for layer-2 agg
        float o1 = b2l;
        #pragma unroll 8
        for (int k = 0; k < H_DIM; ++k) o1 = fmaf(__shfl(t1, k, 64), W2s[k * H_DIM + lane], o1);
        o1 = fmaxf(o1, 0.f);
        float v = 0.f;
        #pragma unroll 8
        for (int k = 0; k < H_DIM; ++k) v = fmaf(__shfl(o1, k, 64), W3s[k * H_DIM + lane], v);
        A[(size_t)n * H_DIM + lane] = v * sc[n];
    }
}

// K7: layer-2 aggregation over both-kept edges: B[dst] += A[src]
__global__ void k7_scatter2(const int* __restrict__ elist, const int* __restrict__ ecount,
                            const int* __restrict__ ei, const float* __restrict__ A,
                            float* __restrict__ B) {
    const int lane = threadIdx.x & 63;
    const int wid  = blockIdx.x * (blockDim.x >> 6) + (threadIdx.x >> 6);
    const int nw   = gridDim.x * (blockDim.x >> 6);
    const int ec = *ecount;
    for (int idx = wid; idx < ec; idx += nw) {
        int e = __builtin_amdgcn_readfirstlane(elist[idx]);
        int s = ei[e];
        int d = ei[N_EDGES + e];
        atomicAdd(&B[(size_t)d * H_DIM + lane], A[(size_t)s * H_DIM + lane]);
    }
}

// K8: kept nodes: t = relu(v + agg2 + b3); o2 = relu(t@W4+b4); gout[g] += o2
__global__ void k8_out(const int* __restrict__ klist, const int* __restrict__ kcount,
                       const int* __restrict__ batch,
                       const float* __restrict__ b3, const float* __restrict__ W4,
                       const float* __restrict__ b4,
                       const float* __restrict__ A, const float* __restrict__ B,
                       float* __restrict__ gout) {
    __shared__ float W4s[H_DIM * H_DIM];
    for (int i = threadIdx.x; i < H_DIM * H_DIM; i += blockDim.x) W4s[i] = W4[i];
    __syncthreads();
    const int lane = threadIdx.x & 63;
    const int wid  = blockIdx.x * (blockDim.x >> 6) + (threadIdx.x >> 6);
    const int nw   = gridDim.x * (blockDim.x >> 6);
    const int kc = *kcount;
    const float b3l = b3[lane], b4l = b4[lane];
    for (int idx = wid; idx < kc; idx += nw) {
        int n = __builtin_amdgcn_readfirstlane(klist[idx]);
        float t = fmaxf(A[(size_t)n * H_DIM + lane] + B[(size_t)n * H_DIM + lane] + b3l, 0.f);
        float o2 = b4l;
        #pragma unroll 8
        for (int k = 0; k < H_DIM; ++k) o2 = fmaf(__shfl(t, k, 64), W4s[k * H_DIM + lane], o2);
        o2 = fmaxf(o2, 0.f);
        atomicAdd(&gout[(size_t)batch[n] * H_DIM + lane], o2);
    }
}

__global__ void k9_final(const float* __restrict__ gout, const float* __restrict__ Wl,
                         const float* __restrict__ bl, const float* __restrict__ klsum,
                         const float* __restrict__ cnt, const int* __restrict__ kcount,
                         float* __restrict__ out) {
    int g = blockIdx.x;
    int lane = threadIdx.x;
    float p = gout[(size_t)g * H_DIM + lane] * Wl[lane];
    #pragma unroll
    for (int m = 32; m > 0; m >>= 1) p += __shfl_xor(p, m, 64);
    if (lane == 0) {
        out[g] = p + bl[0];
        out[G_GRAPHS + g] = klsum[g] / fmaxf(cnt[g], 1.f);
        if (g == 0) out[2 * G_GRAPHS] = (float)(*kcount) * (1.f / (float)N_NODES);
    }
}

extern "C" void kernel_launch(void* const* d_in, const int* in_sizes, int n_in,
                              void* d_out, int out_size, void* d_ws, size_t ws_size,
                              hipStream_t stream) {
    const float* x      = (const float*)d_in[0];
    const int*   ei     = (const int*)d_in[1];
    const int*   batch  = (const int*)d_in[2];
    const float* attn   = (const float*)d_in[3];
    const float* W1     = (const float*)d_in[4];
    const float* b1     = (const float*)d_in[5];
    const float* W2     = (const float*)d_in[6];
    const float* b2     = (const float*)d_in[7];
    const float* pool_w = (const float*)d_in[8];
    const float* W3     = (const float*)d_in[9];
    const float* b3     = (const float*)d_in[10];
    const float* W4     = (const float*)d_in[11];
    const float* b4     = (const float*)d_in[12];
    const float* Wl     = (const float*)d_in[13];
    const float* bl     = (const float*)d_in[14];
    float* out = (float*)d_out;

    // workspace layout
    float* A     = (float*)d_ws;                          // N*64: v at kept rows
    float* B     = A + (size_t)N_NODES * H_DIM;           // N*64: agg1 then agg2 (kept rows only)
    float* sc    = B + (size_t)N_NODES * H_DIM;           // N: raw -> e -> score
    float* mk    = sc + N_NODES;                          // N: mask
    int*   klist = (int*)(mk + N_NODES);                  // N (worst case)
    int*   elist = klist + N_NODES;                       // E (worst case, edge ids)
    // small zeroed block:
    unsigned int* m_enc    = (unsigned int*)(elist + N_EDGES); // G
    float*        z        = (float*)(m_enc + G_GRAPHS);       // G
    unsigned int* smax_enc = (unsigned int*)(z + G_GRAPHS);    // G
    float*        cnt      = (float*)(smax_enc + G_GRAPHS);    // G
    float*        klsum    = cnt + G_GRAPHS;                   // G
    float*        gout     = klsum + G_GRAPHS;                 // G*64
    int*          kcount   = (int*)(gout + (size_t)G_GRAPHS * H_DIM); // 1
    int*          ecount   = kcount + 1;                              // 1
    size_t small_bytes = (size_t)((char*)(ecount + 1) - (char*)m_enc);

    hipMemsetAsync(m_enc, 0, small_bytes, stream);

    k1_pool <<<1024, 256, 0, stream>>>(x, pool_w, batch, sc, m_enc);
    k2_exp  <<<(N_NODES + 255) / 256, 256, 0, stream>>>(batch, m_enc, sc, z);
    k3_score<<<(N_NODES + 255) / 256, 256, 0, stream>>>(batch, z, sc, smax_enc);
    k4_mask <<<(N_NODES + 255) / 256, 256, 0, stream>>>(batch, sc, smax_enc, attn,
                                                        mk, klist, kcount, cnt, klsum, B);
    k5_edges<<<N_EDGES / 256, 256, 0, stream>>>(ei, mk, x, W1, B, elist, ecount);
    k6_kept <<<256, 256, 0, stream>>>(klist, kcount, sc, x, W1, b1, W2, b2, W3, A, B);
    k7_scatter2<<<128, 256, 0, stream>>>(elist, ecount, ei, A, B);
    k8_out  <<<256, 256, 0, stream>>>(klist, kcount, batch, b3, W4, b4, A, B, gout);
    k9_final<<<G_GRAPHS, 64, 0, stream>>>(gout, Wl, bl, klsum, cnt, kcount, out);
}

// Round 4
// 246.116 us; speedup vs baseline: 3.5345x; 2.1552x over previous
//
#include <hip/hip_runtime.h>
#include <math.h>

#define N_NODES 100000
#define N_EDGES 1600000
#define C_IN    128
#define H_DIM   64
#define G_GRAPHS 512
#define MAXG    4096      // max nodes per graph supported in kA LDS (mean 195, ~15x max margin)
#define E2CAP   524288    // kept-dst edge list cap (expected ~8k)
#define ELCAP   65536     // both-kept edge list cap (expected ~tens)
#define KLCAP   16384     // kept node list cap (hard math bound ~10k)

// ---------- graph boundaries from sorted batch ----------
__global__ void kgb(const int* __restrict__ batch, int* __restrict__ gstart) {
    int i = blockIdx.x * blockDim.x + threadIdx.x;
    if (i >= N_NODES) return;
    int bc = batch[i];
    if (i == 0) {
        for (int g = 0; g <= bc; ++g) gstart[g] = 0;
    } else {
        int bp = batch[i - 1];
        for (int g = bp + 1; g <= bc; ++g) gstart[g] = i;
    }
    if (i == N_NODES - 1) {
        for (int g = bc + 1; g <= G_GRAPHS; ++g) gstart[g] = N_NODES;
    }
}

// ---------- raw = x . pool_w (pure BW, no atomics). 2 rows per wave, float4. ----------
__global__ void kraw(const float* __restrict__ x, const float* __restrict__ pool_w,
                     float* __restrict__ sc) {
    const int lane = threadIdx.x & 63;
    const int l32  = lane & 31;
    const int half = lane >> 5;
    const float4 pwv = ((const float4*)pool_w)[l32];
    const int wid = blockIdx.x * (blockDim.x >> 6) + (threadIdx.x >> 6);
    const int nw  = gridDim.x * (blockDim.x >> 6);
    for (int r0 = wid * 2; r0 < N_NODES; r0 += nw * 2) {
        int row = r0 + half;  // N even, r0 even => row < N
        float4 xv = ((const float4*)(x + (size_t)row * C_IN))[l32];
        float pr = xv.x * pwv.x + xv.y * pwv.y + xv.z * pwv.z + xv.w * pwv.w;
        #pragma unroll
        for (int m = 16; m > 0; m >>= 1) pr += __shfl_xor(pr, m, 64);
        if (l32 == 0) sc[row] = pr;
    }
}

// ---------- per-graph softmax + mask + compaction + KL, all block-local ----------
__global__ void kA(const int* __restrict__ gstart, const float* __restrict__ attn,
                   float* __restrict__ sc, unsigned int* __restrict__ kept_bits,
                   int* __restrict__ klist, int* __restrict__ kcount,
                   float* __restrict__ B, float* __restrict__ out) {
    __shared__ float buf[MAXG];
    __shared__ float red[256];
    __shared__ int   lst[64];     // kept per graph <= 20 mathematically
    __shared__ int   cntk;
    __shared__ int   baseS;
    const int g = blockIdx.x;
    const int t = threadIdx.x;
    const int ns = gstart[g], ne = gstart[g + 1];
    const int cn = ne - ns;
    if (cn <= 0) {
        if (t == 0) out[G_GRAPHS + g] = 0.f;
        return;
    }
    // load raw, local max
    float lmax = -3.4e38f;
    for (int i = t; i < cn; i += 256) { float r = sc[ns + i]; buf[i] = r; lmax = fmaxf(lmax, r); }
    red[t] = lmax; __syncthreads();
    for (int o = 128; o > 0; o >>= 1) { if (t < o) red[t] = fmaxf(red[t], red[t + o]); __syncthreads(); }
    float m = red[0]; __syncthreads();
    // e = exp(raw-m), sum
    float lsum = 0.f;
    for (int i = t; i < cn; i += 256) { float e = expf(buf[i] - m); buf[i] = e; lsum += e; }
    red[t] = lsum; __syncthreads();
    for (int o = 128; o > 0; o >>= 1) { if (t < o) red[t] += red[t + o]; __syncthreads(); }
    float z = red[0]; __syncthreads();
    // score = e/z, smax
    float lsm = -3.4e38f;
    for (int i = t; i < cn; i += 256) { float s = buf[i] / z; buf[i] = s; lsm = fmaxf(lsm, s); }
    red[t] = lsm; __syncthreads();
    for (int o = 128; o > 0; o >>= 1) { if (t < o) red[t] = fmaxf(red[t], red[t + o]); __syncthreads(); }
    float smax = red[0];
    float thresh = fminf(smax - 1e-7f, 0.05f);
    if (t == 0) cntk = 0;
    __syncthreads();
    // mask + kept compaction + KL
    float klacc = 0.f;
    for (int i = t; i < cn; i += 256) {
        float s = buf[i];
        int n = ns + i;
        sc[n] = s;
        if (s > thresh) {
            int p = atomicAdd(&cntk, 1);
            if (p < 64) lst[p] = i;
            float a = attn[n];
            klacc += a * (logf(a) - logf(s + 1e-14f));
        }
    }
    red[t] = klacc; __syncthreads();
    for (int o = 128; o > 0; o >>= 1) { if (t < o) red[t] += red[t + o]; __syncthreads(); }
    int kc = cntk;
    if (t == 0) {
        out[G_GRAPHS + g] = (kc > 0) ? red[0] / (float)kc : 0.f;
        baseS = (kc > 0) ? atomicAdd(kcount, kc) : 0;
    }
    __syncthreads();
    int base = baseS;
    int kcc = kc < 64 ? kc : 64;
    for (int i = t; i < kcc; i += 256) {
        int n = ns + lst[i];
        if (base + i < KLCAP) klist[base + i] = n;
        atomicOr(&kept_bits[n >> 5], 1u << (n & 31));
    }
    __syncthreads();
    for (int j = t; j < kcc * H_DIM; j += 256)
        B[(size_t)(ns + lst[j >> 6]) * H_DIM + (j & 63)] = 0.f;
}

// ---------- edge scan with L1-resident bitmask, block-aggregated compaction ----------
__global__ void k5a(const int* __restrict__ ei, const unsigned int* __restrict__ bits,
                    int* __restrict__ e2sd, int* __restrict__ e2count,
                    int* __restrict__ elsd, int* __restrict__ elcount) {
    __shared__ int ls[256], ld[256];
    __shared__ int l2s[256], l2d[256];
    __shared__ int c1, c2, b1s, b2s;
    if (threadIdx.x == 0) { c1 = 0; c2 = 0; }
    __syncthreads();
    int e = blockIdx.x * 256 + threadIdx.x;
    int s = 0, d = 0;
    bool kd = false, ks2 = false;
    if (e < N_EDGES) {
        s = ei[e]; d = ei[N_EDGES + e];
        kd = (bits[d >> 5] >> (d & 31)) & 1u;
        if (kd) ks2 = (bits[s >> 5] >> (s & 31)) & 1u;
    }
    if (kd)         { int p = atomicAdd(&c1, 1); ls[p] = s; ld[p] = d; }
    if (kd && ks2)  { int p = atomicAdd(&c2, 1); l2s[p] = s; l2d[p] = d; }
    __syncthreads();
    if (threadIdx.x == 0) {
        b1s = (c1 > 0) ? atomicAdd(e2count, c1) : 0;
        b2s = (c2 > 0) ? atomicAdd(elcount, c2) : 0;
    }
    __syncthreads();
    for (int i = threadIdx.x; i < c1; i += 256) {
        int p = b1s + i;
        if (p < E2CAP) { e2sd[p] = ls[i]; e2sd[E2CAP + p] = ld[i]; }
    }
    for (int i = threadIdx.x; i < c2; i += 256) {
        int p = b2s + i;
        if (p < ELCAP) { elsd[p] = l2s[i]; elsd[ELCAP + p] = l2d[i]; }
    }
}

// ---------- layer-1 agg for kept-dst edges: B[dst] += x[src]@W1 ----------
__global__ void k5b(const int* __restrict__ e2sd, const int* __restrict__ e2count,
                    const float* __restrict__ x, const float* __restrict__ W1,
                    float* __restrict__ B) {
    __shared__ float W1s[C_IN * H_DIM];
    for (int i = threadIdx.x; i < C_IN * H_DIM; i += blockDim.x) W1s[i] = W1[i];
    __syncthreads();
    const int lane = threadIdx.x & 63;
    const int wid  = blockIdx.x * (blockDim.x >> 6) + (threadIdx.x >> 6);
    const int nw   = gridDim.x * (blockDim.x >> 6);
    int ec = *e2count; if (ec > E2CAP) ec = E2CAP;
    for (int idx = wid; idx < ec; idx += nw) {
        int s = __builtin_amdgcn_readfirstlane(e2sd[idx]);
        int d = __builtin_amdgcn_readfirstlane(e2sd[E2CAP + idx]);
        const float4* xr = (const float4*)(x + (size_t)s * C_IN);
        float acc = 0.f;
        #pragma unroll 8
        for (int k4 = 0; k4 < C_IN / 4; ++k4) {
            float4 xv = xr[k4];
            acc = fmaf(xv.x, W1s[(4 * k4 + 0) * H_DIM + lane], acc);
            acc = fmaf(xv.y, W1s[(4 * k4 + 1) * H_DIM + lane], acc);
            acc = fmaf(xv.z, W1s[(4 * k4 + 2) * H_DIM + lane], acc);
            acc = fmaf(xv.w, W1s[(4 * k4 + 3) * H_DIM + lane], acc);
        }
        atomicAdd(&B[(size_t)d * H_DIM + lane], acc);
    }
}

// ---------- kept nodes: full layer-1 MLP + W3 projection ----------
__global__ void k6_kept(const int* __restrict__ klist, const int* __restrict__ kcount,
                        const float* __restrict__ sc, const float* __restrict__ x,
                        const float* __restrict__ W1,
                        const float* __restrict__ b1, const float* __restrict__ W2,
                        const float* __restrict__ b2, const float* __restrict__ W3,
                        float* __restrict__ A, float* __restrict__ B) {
    __shared__ float W1s[C_IN * H_DIM];
    __shared__ float W2s[H_DIM * H_DIM];
    __shared__ float W3s[H_DIM * H_DIM];
    for (int i = threadIdx.x; i < C_IN * H_DIM; i += blockDim.x) W1s[i] = W1[i];
    for (int i = threadIdx.x; i < H_DIM * H_DIM; i += blockDim.x) {
        W2s[i] = W2[i];
        W3s[i] = W3[i];
    }
    __syncthreads();
    const int lane = threadIdx.x & 63;
    const int wid  = blockIdx.x * (blockDim.x >> 6) + (threadIdx.x >> 6);
    const int nw   = gridDim.x * (blockDim.x >> 6);
    int kc = *kcount; if (kc > KLCAP) kc = KLCAP;
    const float b1l = b1[lane], b2l = b2[lane];
    for (int idx = wid; idx < kc; idx += nw) {
        int n = __builtin_amdgcn_readfirstlane(klist[idx]);
        const float4* xr = (const float4*)(x + (size_t)n * C_IN);
        float u = 0.f;
        #pragma unroll 8
        for (int k4 = 0; k4 < C_IN / 4; ++k4) {
            float4 xv = xr[k4];
            u = fmaf(xv.x, W1s[(4 * k4 + 0) * H_DIM + lane], u);
            u = fmaf(xv.y, W1s[(4 * k4 + 1) * H_DIM + lane], u);
            u = fmaf(xv.z, W1s[(4 * k4 + 2) * H_DIM + lane], u);
            u = fmaf(xv.w, W1s[(4 * k4 + 3) * H_DIM + lane], u);
        }
        float t1 = fmaxf(u + B[(size_t)n * H_DIM + lane] + b1l, 0.f);
        B[(size_t)n * H_DIM + lane] = 0.f;  // reset for layer-2 agg
        float o1 = b2l;
        #pragma unroll 8
        for (int k = 0; k < H_DIM; ++k) o1 = fmaf(__shfl(t1, k, 64), W2s[k * H_DIM + lane], o1);
        o1 = fmaxf(o1, 0.f);
        float v = 0.f;
        #pragma unroll 8
        for (int k = 0; k < H_DIM; ++k) v = fmaf(__shfl(o1, k, 64), W3s[k * H_DIM + lane], v);
        A[(size_t)n * H_DIM + lane] = v * sc[n];
    }
}

// ---------- layer-2 agg over both-kept edges ----------
__global__ void k7_scatter2(const int* __restrict__ elsd, const int* __restrict__ elcount,
                            const float* __restrict__ A, float* __restrict__ B) {
    const int lane = threadIdx.x & 63;
    const int wid  = blockIdx.x * (blockDim.x >> 6) + (threadIdx.x >> 6);
    const int nw   = gridDim.x * (blockDim.x >> 6);
    int ec = *elcount; if (ec > ELCAP) ec = ELCAP;
    for (int idx = wid; idx < ec; idx += nw) {
        int s = __builtin_amdgcn_readfirstlane(elsd[idx]);
        int d = __builtin_amdgcn_readfirstlane(elsd[ELCAP + idx]);
        atomicAdd(&B[(size_t)d * H_DIM + lane], A[(size_t)s * H_DIM + lane]);
    }
}

// ---------- kept nodes: layer-2 MLP + global_add_pool ----------
__global__ void k8_out(const int* __restrict__ klist, const int* __restrict__ kcount,
                       const int* __restrict__ batch,
                       const float* __restrict__ b3, const float* __restrict__ W4,
                       const float* __restrict__ b4,
                       const float* __restrict__ A, const float* __restrict__ B,
                       float* __restrict__ gout) {
    __shared__ float W4s[H_DIM * H_DIM];
    for (int i = threadIdx.x; i < H_DIM * H_DIM; i += blockDim.x) W4s[i] = W4[i];
    __syncthreads();
    const int lane = threadIdx.x & 63;
    const int wid  = blockIdx.x * (blockDim.x >> 6) + (threadIdx.x >> 6);
    const int nw   = gridDim.x * (blockDim.x >> 6);
    int kc = *kcount; if (kc > KLCAP) kc = KLCAP;
    const float b3l = b3[lane], b4l = b4[lane];
    for (int idx = wid; idx < kc; idx += nw) {
        int n = __builtin_amdgcn_readfirstlane(klist[idx]);
        float t = fmaxf(A[(size_t)n * H_DIM + lane] + B[(size_t)n * H_DIM + lane] + b3l, 0.f);
        float o2 = b4l;
        #pragma unroll 8
        for (int k = 0; k < H_DIM; ++k) o2 = fmaf(__shfl(t, k, 64), W4s[k * H_DIM + lane], o2);
        o2 = fmaxf(o2, 0.f);
        atomicAdd(&gout[(size_t)batch[n] * H_DIM + lane], o2);
    }
}

__global__ void k9_final(const float* __restrict__ gout, const float* __restrict__ Wl,
                         const float* __restrict__ bl, const int* __restrict__ kcount,
                         float* __restrict__ out) {
    int g = blockIdx.x;
    int lane = threadIdx.x;
    float p = gout[(size_t)g * H_DIM + lane] * Wl[lane];
    #pragma unroll
    for (int m = 32; m > 0; m >>= 1) p += __shfl_xor(p, m, 64);
    if (lane == 0) {
        out[g] = p + bl[0];
        if (g == 0) out[2 * G_GRAPHS] = (float)(*kcount) * (1.f / (float)N_NODES);
    }
}

extern "C" void kernel_launch(void* const* d_in, const int* in_sizes, int n_in,
                              void* d_out, int out_size, void* d_ws, size_t ws_size,
                              hipStream_t stream) {
    const float* x      = (const float*)d_in[0];
    const int*   ei     = (const int*)d_in[1];
    const int*   batch  = (const int*)d_in[2];
    const float* attn   = (const float*)d_in[3];
    const float* W1     = (const float*)d_in[4];
    const float* b1     = (const float*)d_in[5];
    const float* W2     = (const float*)d_in[6];
    const float* b2     = (const float*)d_in[7];
    const float* pool_w = (const float*)d_in[8];
    const float* W3     = (const float*)d_in[9];
    const float* b3     = (const float*)d_in[10];
    const float* W4     = (const float*)d_in[11];
    const float* b4     = (const float*)d_in[12];
    const float* Wl     = (const float*)d_in[13];
    const float* bl     = (const float*)d_in[14];
    float* out = (float*)d_out;

    // workspace layout (total ~56 MB)
    float* A      = (float*)d_ws;                       // N*64 (kept rows only used)
    float* B      = A + (size_t)N_NODES * H_DIM;        // N*64 (kept rows only used)
    float* sc     = B + (size_t)N_NODES * H_DIM;        // N: raw -> score
    int*   gstart = (int*)(sc + N_NODES);               // G+1
    int*   klist  = gstart + (G_GRAPHS + 1);            // KLCAP
    int*   e2sd   = klist + KLCAP;                      // 2*E2CAP (src block, dst block)
    int*   elsd   = e2sd + 2 * E2CAP;                   // 2*ELCAP
    // zeroed block:
    unsigned int* kept_bits = (unsigned int*)(elsd + 2 * ELCAP);   // N/32 = 3125
    float*        gout      = (float*)(kept_bits + 3136);          // G*64
    int*          kcount    = (int*)(gout + (size_t)G_GRAPHS * H_DIM);
    int*          e2count   = kcount + 1;
    int*          elcount   = e2count + 1;
    size_t zero_bytes = (size_t)((char*)(elcount + 1) - (char*)kept_bits);

    hipMemsetAsync(kept_bits, 0, zero_bytes, stream);

    kgb  <<<(N_NODES + 255) / 256, 256, 0, stream>>>(batch, gstart);
    kraw <<<2048, 256, 0, stream>>>(x, pool_w, sc);
    kA   <<<G_GRAPHS, 256, 0, stream>>>(gstart, attn, sc, kept_bits, klist, kcount, B, out);
    k5a  <<<(N_EDGES + 255) / 256, 256, 0, stream>>>(ei, kept_bits, e2sd, e2count, elsd, elcount);
    k5b  <<<512, 256, 0, stream>>>(e2sd, e2count, x, W1, B);
    k6_kept<<<64, 256, 0, stream>>>(klist, kcount, sc, x, W1, b1, W2, b2, W3, A, B);
    k7_scatter2<<<64, 256, 0, stream>>>(elsd, elcount, A, B);
    k8_out<<<64, 256, 0, stream>>>(klist, kcount, batch, b3, W4, b4, A, B, gout);
    k9_final<<<G_GRAPHS, 64, 0, stream>>>(gout, Wl, bl, kcount, out);
}